// Round 9
// baseline (443.756 us; speedup 1.0000x reference)
//
#include <hip/hip_runtime.h>
#include <hip/hip_cooperative_groups.h>

// GNN surrogate — cooperative single-kernel (prep phase + grid.sync + strided
// batch loop), with occupancy-derived grid and a checked fallback to the
// round-7 two-kernel path if the cooperative launch is rejected.
// Folds (exact): M_l = W2[l]@W1[l+1] (adj row-normalized -> biases commute
// through aggregation), lift absorbed into W1eff (K=3 pad 32),
// v[j]=mean_i adj[i,j], u=W2[2]@W_ro, cp=(b2[2]·W_ro)*sum(v)+b_ro.
// Layout rule: state is always the MFMA A-operand; C-frag writes land
// contiguously in the transposed buffer = next stage's contiguous A-read.

namespace cg = cooperative_groups;

typedef _Float16 f16;
typedef __attribute__((ext_vector_type(8))) _Float16 half8;
typedef __attribute__((ext_vector_type(4))) _Float16 half4;
typedef __attribute__((ext_vector_type(2))) __fp16 fp16x2;   // cvt_pkrtz native
typedef __attribute__((ext_vector_type(4))) float f32x4;

namespace {
constexpr int N = 128, H = 32;
// ws byte layout
constexpr int WS_ADJF = 0;       // f16 [128][128] adj row-major        (32768 B)
constexpr int WS_WFB  = 32768;   // f16 [3][2][64][8] B-frag-ordered Meff (6144 B)
constexpr int WS_BIAS = 38912;   // f32 [3][32] folded biases            (384 B)
constexpr int WS_V    = 39424;   // f32 [128] v[j]=mean_i adj[i][j]      (512 B)
constexpr int WS_U    = 39936;   // f32 [32]  u[k]=sum_c W2[2][k][c]W_ro (128 B)
constexpr int WS_C    = 40064;   // f32 [1]
constexpr int TS = 152;  // bufT row stride f16 (304 B)
constexpr int PS = 40;   // bufP row stride f16 (80 B)
}

static __device__ __forceinline__ half4 pk4(float a, float b, float c, float d) {
  union { half4 v; fp16x2 h[2]; } u;
  u.h[0] = __builtin_amdgcn_cvt_pkrtz(a, b);
  u.h[1] = __builtin_amdgcn_cvt_pkrtz(c, d);
  return u.v;
}
static __device__ __forceinline__ half4 relu4(half4 v) {
  const half4 z = {};
  return __builtin_elementwise_max(v, z);
}

// ---- the 5-stage chain over a strided batch range (shared by both paths) ----
static __device__ __forceinline__ void run_batches(
    const float* __restrict__ x, const char* __restrict__ ws,
    float* __restrict__ out, f16* slab,
    int slot, int stride, int nbatch, int lane, int lrow, int quad) {
  const f16* adjf  = (const f16*)(ws + WS_ADJF);
  const f16* wfb   = (const f16*)(ws + WS_WFB);
  const float* bia = (const float*)(ws + WS_BIAS);
  const float* v   = (const float*)(ws + WS_V);
  const float* u   = (const float*)(ws + WS_U);
  const f32x4 zero = {0.f, 0.f, 0.f, 0.f};

  // hoisted invariants (live across the batch loop)
  const half8 w0l0 = *(const half8*)(wfb + 0 * 1024 + 0 * 512 + lane * 8);
  const half8 w1l0 = *(const half8*)(wfb + 0 * 1024 + 1 * 512 + lane * 8);
  const half8 w0l1 = *(const half8*)(wfb + 1 * 1024 + 0 * 512 + lane * 8);
  const half8 w1l1 = *(const half8*)(wfb + 1 * 1024 + 1 * 512 + lane * 8);
  const half8 w0l2 = *(const half8*)(wfb + 2 * 1024 + 0 * 512 + lane * 8);
  const half8 w1l2 = *(const half8*)(wfb + 2 * 1024 + 1 * 512 + lane * 8);
  const f32x4 bi0l0 = {bia[lrow], bia[lrow], bia[lrow], bia[lrow]};
  const f32x4 bi1l0 = {bia[16 + lrow], bia[16 + lrow], bia[16 + lrow], bia[16 + lrow]};
  const float bb0l1 = bia[H + lrow],     bb1l1 = bia[H + 16 + lrow];
  const float bb0l2 = bia[2 * H + lrow], bb1l2 = bia[2 * H + 16 + lrow];
  const f32x4 bi0l1 = {bb0l1, bb0l1, bb0l1, bb0l1};
  const f32x4 bi1l1 = {bb1l1, bb1l1, bb1l1, bb1l1};
  const f32x4 bi0l2 = {bb0l2, bb0l2, bb0l2, bb0l2};
  const f32x4 bi1l2 = {bb1l2, bb1l2, bb1l2, bb1l2};
  const float u0 = u[lrow], u1 = u[16 + lrow];
  const float cp0 = *(const float*)(ws + WS_C);

  fp16x2 xp[8][2];   // x prefetch (only quad==0 lanes hold real data)
  if (slot < nbatch && quad == 0) {
    const float* xb = x + (size_t)slot * (N * 3);
#pragma unroll
    for (int g = 0; g < 8; ++g) {
      const float* xr = xb + (g * 16 + lrow) * 3;
      xp[g][0] = __builtin_amdgcn_cvt_pkrtz(xr[0], xr[1]);
      xp[g][1] = __builtin_amdgcn_cvt_pkrtz(xr[2], 0.f);
    }
  }

  for (int b = slot; b < nbatch; b += stride) {
    // ---- L0: T0 = relu(x·W1eff + b0) -> bufT[fout][node] ----
#pragma unroll
    for (int g = 0; g < 8; ++g) {
      union { half8 v8; fp16x2 p[4]; } xa;
      xa.v8 = (half8){};
      if (quad == 0) { xa.p[0] = xp[g][0]; xa.p[1] = xp[g][1]; }
      const f32x4 c0 = __builtin_amdgcn_mfma_f32_16x16x32_f16(xa.v8, w0l0, bi0l0, 0, 0, 0);
      const f32x4 c1 = __builtin_amdgcn_mfma_f32_16x16x32_f16(xa.v8, w1l0, bi1l0, 0, 0, 0);
      *(half4*)(slab + lrow * TS + g * 16 + quad * 4)        = relu4(pk4(c0[0], c0[1], c0[2], c0[3]));
      *(half4*)(slab + (16 + lrow) * TS + g * 16 + quad * 4) = relu4(pk4(c1[0], c1[1], c1[2], c1[3]));
    }

    // ---- G0: P0^T=T0^T·adj^T -> bufP; L1: T1=relu(P0·M0+c0) -> bufT; G1 ----
#pragma unroll
    for (int l = 0; l < 2; ++l) {
      {
        half8 aT[2][4];
#pragma unroll
        for (int t = 0; t < 2; ++t)
#pragma unroll
          for (int kt = 0; kt < 4; ++kt)
            aT[t][kt] = *(const half8*)(slab + (t * 16 + lrow) * TS + kt * 32 + quad * 8);
#pragma unroll
        for (int g = 0; g < 8; ++g) {
          f32x4 a0 = zero, a1 = zero;
#pragma unroll
          for (int kt = 0; kt < 4; ++kt) {
            const half8 bf = *(const half8*)(adjf + (g * 16 + lrow) * N + kt * 32 + quad * 8);
            a0 = __builtin_amdgcn_mfma_f32_16x16x32_f16(aT[0][kt], bf, a0, 0, 0, 0);
            a1 = __builtin_amdgcn_mfma_f32_16x16x32_f16(aT[1][kt], bf, a1, 0, 0, 0);
          }
          f16* prow = slab + (g * 16 + lrow) * PS;
          *(half4*)(prow + quad * 4)      = pk4(a0[0], a0[1], a0[2], a0[3]);
          *(half4*)(prow + 16 + quad * 4) = pk4(a1[0], a1[1], a1[2], a1[3]);
        }
      }
      if (l == 1) break;
      {
        half8 af[8];
#pragma unroll
        for (int g = 0; g < 8; ++g)
          af[g] = *(const half8*)(slab + (g * 16 + lrow) * PS + quad * 8);
#pragma unroll
        for (int g = 0; g < 8; ++g) {
          const f32x4 c0 = __builtin_amdgcn_mfma_f32_16x16x32_f16(af[g], w0l1, bi0l1, 0, 0, 0);
          const f32x4 c1 = __builtin_amdgcn_mfma_f32_16x16x32_f16(af[g], w1l1, bi1l1, 0, 0, 0);
          *(half4*)(slab + lrow * TS + g * 16 + quad * 4)        = relu4(pk4(c0[0], c0[1], c0[2], c0[3]));
          *(half4*)(slab + (16 + lrow) * TS + g * 16 + quad * 4) = relu4(pk4(c1[0], c1[1], c1[2], c1[3]));
        }
      }
    }

    // prefetch next batch's x while P1 settles
    if (quad == 0 && b + stride < nbatch) {
      const float* xb = x + (size_t)(b + stride) * (N * 3);
#pragma unroll
      for (int g = 0; g < 8; ++g) {
        const float* xr = xb + (g * 16 + lrow) * 3;
        xp[g][0] = __builtin_amdgcn_cvt_pkrtz(xr[0], xr[1]);
        xp[g][1] = __builtin_amdgcn_cvt_pkrtz(xr[2], 0.f);
      }
    }

    // ---- L2 + folded readout ----
    {
      float partial = 0.f;
#pragma unroll
      for (int g = 0; g < 8; ++g) {
        const half8 af = *(const half8*)(slab + (g * 16 + lrow) * PS + quad * 8);
        const f32x4 c0 = __builtin_amdgcn_mfma_f32_16x16x32_f16(af, w0l2, bi0l2, 0, 0, 0);
        const f32x4 c1 = __builtin_amdgcn_mfma_f32_16x16x32_f16(af, w1l2, bi1l2, 0, 0, 0);
        const float4 vv = *(const float4*)(v + g * 16 + quad * 4);
        const float s0 = fmaxf(c0[0], 0.f) * vv.x + fmaxf(c0[1], 0.f) * vv.y +
                         fmaxf(c0[2], 0.f) * vv.z + fmaxf(c0[3], 0.f) * vv.w;
        const float s1 = fmaxf(c1[0], 0.f) * vv.x + fmaxf(c1[1], 0.f) * vv.y +
                         fmaxf(c1[2], 0.f) * vv.z + fmaxf(c1[3], 0.f) * vv.w;
        partial += s0 * u0 + s1 * u1;
      }
#pragma unroll
      for (int off = 32; off > 0; off >>= 1) partial += __shfl_down(partial, off, 64);
      if (lane == 0) out[b] = partial + cp0;
    }
  }
}

// ================= cooperative single-kernel path =================
__global__ __launch_bounds__(256, 4)
void gnn_coop(const float* __restrict__ x,
              const float* __restrict__ adj,
              const float* __restrict__ W_lift,
              const float* __restrict__ b_lift,
              const float* __restrict__ W1,
              const float* __restrict__ b1,
              const float* __restrict__ W2,
              const float* __restrict__ b2,
              const float* __restrict__ W_ro,
              const float* __restrict__ b_ro,
              char* __restrict__ ws,
              float* __restrict__ out,
              int nbatch) {
  __shared__ f16 smem[4][5120];

  const int tid  = threadIdx.x;
  const int blk  = blockIdx.x;
  const int wave = tid >> 6;
  const int lane = tid & 63;
  const int lrow = lane & 15;
  const int quad = lane >> 4;

  // ---- phase 0: distributed prep into ws ----
  {
    f16*   adjfw = (f16*)(ws + WS_ADJF);
    f16*   wfbw  = (f16*)(ws + WS_WFB);
    float* biaw  = (float*)(ws + WS_BIAS);
    float* vw    = (float*)(ws + WS_V);
    float* uw    = (float*)(ws + WS_U);
    float* cpw   = (float*)(ws + WS_C);

    const int gid = blk * 256 + tid;
    if (gid < N * N) adjfw[gid] = (f16)adj[gid];   // blocks 0..63

    if (blk == 64) {
      float* tmp  = (float*)&smem[0][0];   // [3][32][32] fp32 scratch
      float* sred = tmp + 3 * H * H;       // [128]
      for (int idx = tid; idx < 3 * H * H; idx += 256) {
        const int l = idx >> 10, rem = idx & 1023;
        const int k = rem >> 5, fo = rem & 31;
        float val = 0.f;
        if (l == 0) {
          if (k < 3) for (int c = 0; c < H; ++c) val += W_lift[k * H + c] * W1[c * H + fo];
        } else {
          const float* w2l = W2 + (l - 1) * H * H;
          const float* w1n = W1 + l * H * H;
          for (int c = 0; c < H; ++c) val += w2l[k * H + c] * w1n[c * H + fo];
        }
        tmp[idx] = val;
      }
      if (tid < N) {
        float s = 0.f;
        for (int i = 0; i < N; ++i) s += adj[i * N + tid];
        vw[tid] = s * (1.0f / N);
        sred[tid] = s * (1.0f / N);
      }
      if (tid < H) {
        float s0 = b1[tid], s1 = b1[H + tid], s2 = b1[2 * H + tid];
        for (int c = 0; c < H; ++c) {
          s0 += b_lift[c] * W1[c * H + tid];
          s1 += b2[c] * W1[H * H + c * H + tid];
          s2 += b2[H + c] * W1[2 * H * H + c * H + tid];
        }
        biaw[tid] = s0; biaw[H + tid] = s1; biaw[2 * H + tid] = s2;
        float su = 0.f;
        for (int c = 0; c < H; ++c) su += W2[2 * H * H + tid * H + c] * W_ro[c];
        uw[tid] = su;
      }
      __syncthreads();
      for (int idx = tid; idx < 3 * 1024; idx += 256) {
        const int l = idx >> 10, rem = idx & 1023;
        const int t = rem >> 9, ln = (rem >> 3) & 63, j = rem & 7;
        const int q = ln >> 4, lr = ln & 15;
        wfbw[idx] = (f16)tmp[l * 1024 + (q * 8 + j) * 32 + (t * 16 + lr)];
      }
      if (tid == 0) {
        float c2r = 0.f;
        for (int k = 0; k < H; ++k) c2r += b2[2 * H + k] * W_ro[k];
        float S = 0.f;
        for (int j = 0; j < N; ++j) S += sred[j];
        cpw[0] = c2r * S + b_ro[0];
      }
    }
  }
  cg::this_grid().sync();

  const int stride = (int)gridDim.x * 4;
  run_batches(x, (const char*)ws, out, &smem[wave][0],
              blk * 4 + wave, stride, nbatch, lane, lrow, quad);
}

// ================= fallback two-kernel path (round-7, known good) =========
__global__ void prep(const float* __restrict__ adj,
                     const float* __restrict__ W_lift,
                     const float* __restrict__ b_lift,
                     const float* __restrict__ W1,
                     const float* __restrict__ b1,
                     const float* __restrict__ W2,
                     const float* __restrict__ b2,
                     const float* __restrict__ W_ro,
                     const float* __restrict__ b_ro,
                     char* __restrict__ ws) {
  const int tid = threadIdx.x;
  const int gid = blockIdx.x * 256 + tid;
  f16* adjf  = (f16*)(ws + WS_ADJF);
  f16* wfb   = (f16*)(ws + WS_WFB);
  float* bia = (float*)(ws + WS_BIAS);
  float* v   = (float*)(ws + WS_V);
  float* u   = (float*)(ws + WS_U);
  float* cp  = (float*)(ws + WS_C);

  for (int idx = gid; idx < N * N; idx += 2048) adjf[idx] = (f16)adj[idx];

  if (blockIdx.x == 0) {
    __shared__ float tmp[3][H][H];
    __shared__ float sred[N];
    for (int idx = tid; idx < 3 * H * H; idx += 256) {
      const int l = idx >> 10, rem = idx & 1023;
      const int k = rem >> 5, fo = rem & 31;
      float val = 0.f;
      if (l == 0) {
        if (k < 3) for (int c = 0; c < H; ++c) val += W_lift[k * H + c] * W1[c * H + fo];
      } else {
        const float* w2l = W2 + (l - 1) * H * H;
        const float* w1n = W1 + l * H * H;
        for (int c = 0; c < H; ++c) val += w2l[k * H + c] * w1n[c * H + fo];
      }
      tmp[l][k][fo] = val;
    }
    if (tid < N) {
      float s = 0.f;
      for (int i = 0; i < N; ++i) s += adj[i * N + tid];
      v[tid] = s * (1.0f / N);
      sred[tid] = s * (1.0f / N);
    }
    if (tid < H) {
      float s0 = b1[tid], s1 = b1[H + tid], s2 = b1[2 * H + tid];
      for (int c = 0; c < H; ++c) {
        s0 += b_lift[c] * W1[c * H + tid];
        s1 += b2[c] * W1[H * H + c * H + tid];
        s2 += b2[H + c] * W1[2 * H * H + c * H + tid];
      }
      bia[tid] = s0; bia[H + tid] = s1; bia[2 * H + tid] = s2;
      float su = 0.f;
      for (int c = 0; c < H; ++c) su += W2[2 * H * H + tid * H + c] * W_ro[c];
      u[tid] = su;
    }
    __syncthreads();
    for (int idx = tid; idx < 3 * 1024; idx += 256) {
      const int l = idx >> 10, rem = idx & 1023;
      const int t = rem >> 9, ln = (rem >> 3) & 63, j = rem & 7;
      const int q = ln >> 4, lr = ln & 15;
      wfb[idx] = (f16)tmp[l][q * 8 + j][t * 16 + lr];
    }
    if (tid == 0) {
      float c2r = 0.f;
      for (int k = 0; k < H; ++k) c2r += b2[2 * H + k] * W_ro[k];
      float S = 0.f;
      for (int j = 0; j < N; ++j) S += sred[j];
      cp[0] = c2r * S + b_ro[0];
    }
  }
}

__global__ __launch_bounds__(256, 4)
void gnn_main(const float* __restrict__ x,
              const char* __restrict__ ws,
              float* __restrict__ out,
              int nbatch) {
  __shared__ f16 smem[4][5120];
  const int tid  = threadIdx.x;
  const int wave = tid >> 6;
  const int lane = tid & 63;
  const int stride = (int)gridDim.x * 4;
  run_batches(x, ws, out, &smem[wave][0],
              (int)blockIdx.x * 4 + wave, stride, nbatch,
              lane, lane & 15, lane >> 4);
}

extern "C" void kernel_launch(void* const* d_in, const int* in_sizes, int n_in,
                              void* d_out, int out_size, void* d_ws, size_t ws_size,
                              hipStream_t stream) {
  const float* x      = (const float*)d_in[0];
  const float* adj    = (const float*)d_in[1];
  const float* W_lift = (const float*)d_in[2];
  const float* b_lift = (const float*)d_in[3];
  const float* W1     = (const float*)d_in[4];
  const float* b1     = (const float*)d_in[5];
  const float* W2     = (const float*)d_in[6];
  const float* b2     = (const float*)d_in[7];
  const float* W_ro   = (const float*)d_in[8];
  const float* b_ro   = (const float*)d_in[9];
  char* ws = (char*)d_ws;
  float* o = (float*)d_out;
  int nbatch = in_sizes[0] / (N * 3);   // 16384

  // occupancy-derived cooperative grid (never exceeds co-residency)
  int maxb = 0;
  hipError_t oe = hipOccupancyMaxActiveBlocksPerMultiprocessor(
      &maxb, (const void*)gnn_coop, 256, 0);
  int grid = maxb * 256;               // 256 CUs on MI355X
  if (grid > nbatch / 4) grid = nbatch / 4;
  if (oe == hipSuccess && grid >= 65) {
    void* args[] = {(void*)&x, (void*)&adj, (void*)&W_lift, (void*)&b_lift,
                    (void*)&W1, (void*)&b1, (void*)&W2, (void*)&b2,
                    (void*)&W_ro, (void*)&b_ro, (void*)&ws, (void*)&o,
                    (void*)&nbatch};
    hipError_t le = hipLaunchCooperativeKernel((const void*)gnn_coop,
                                               dim3(grid), dim3(256),
                                               args, 0, stream);
    if (le == hipSuccess) return;
  }
  // fallback: round-7 two-kernel path
  hipLaunchKernelGGL(prep, dim3(8), dim3(256), 0, stream,
                     adj, W_lift, b_lift, W1, b1, W2, b2, W_ro, b_ro, ws);
  hipLaunchKernelGGL(gnn_main, dim3(nbatch / 4), dim3(256), 0, stream,
                     x, (const char*)ws, o, nbatch);
}